// Round 21
// baseline (203.597 us; speedup 1.0000x reference)
//
#include <hip/hip_runtime.h>
#include <hip/hip_bf16.h>
#include <cfloat>

// dims
#define N_B 32
#define QN 64
#define FN 16
#define LP 196
#define HN 12
#define DH 64
#define EE 768
#define KLEN 3136
#define FPB 4          // frames per block (attn): 12*4*32 = 1536 blocks = 3.0 CU-rounds @2/CU
#define KROWS 208      // padded patches per frame for QK (13*16)
#define VST 256        // Vt_s row stride in bf16 (512B, pow2 for XOR swizzle)

typedef short s16x4 __attribute__((ext_vector_type(4)));
typedef __bf16 bf16x4 __attribute__((ext_vector_type(4)));
typedef __bf16 bf16x8 __attribute__((ext_vector_type(8)));
typedef float f32x4 __attribute__((ext_vector_type(4)));
typedef unsigned u32x2 __attribute__((ext_vector_type(2)));

__device__ __forceinline__ bf16x8 cvt8(f32x4 a, f32x4 b) {
    bf16x8 r;
    r[0] = (__bf16)a[0]; r[1] = (__bf16)a[1]; r[2] = (__bf16)a[2]; r[3] = (__bf16)a[3];
    r[4] = (__bf16)b[0]; r[5] = (__bf16)b[1]; r[6] = (__bf16)b[2]; r[7] = (__bf16)b[3];
    return r;
}
__device__ __forceinline__ unsigned short bfb(float x) {
    return __builtin_bit_cast(unsigned short, (__bf16)x);
}
__device__ __forceinline__ unsigned pkbf(float lo, float hi) {
    return (unsigned)bfb(lo) | ((unsigned)bfb(hi) << 16);
}
// raw workgroup barrier that does NOT drain vmcnt (LDS ordering only).
__device__ __forceinline__ void barrier_lds_only() {
    asm volatile("s_waitcnt lgkmcnt(0)" ::: "memory");
    __builtin_amdgcn_s_barrier();
    __builtin_amdgcn_sched_barrier(0);  // rule #18: nothing hoists past the waitcnt
}

// 16x16x16 bf16 MFMA with name-portability fallback
__device__ __forceinline__ f32x4 mfma16(s16x4 a, s16x4 b, f32x4 c) {
#if __has_builtin(__builtin_amdgcn_mfma_f32_16x16x16_bf16)
    return __builtin_amdgcn_mfma_f32_16x16x16_bf16(__builtin_bit_cast(bf16x4, a),
                                                   __builtin_bit_cast(bf16x4, b), c, 0, 0, 0);
#elif __has_builtin(__builtin_amdgcn_mfma_f32_16x16x16bf16_1k)
    return __builtin_amdgcn_mfma_f32_16x16x16bf16_1k(a, b, c, 0, 0, 0);
#else
    f32x4 d;
    asm volatile("v_mfma_f32_16x16x16_bf16 %0, %1, %2, %3"
                 : "=v"(d) : "v"(a), "v"(b), "v"(c));
    return d;
#endif
}

// ---------------------------------------------------------------------------
// bf16 MFMA GEMM: C[m][n] = sum_k A[m][k] * W[n][k]  (fp32 in, fp32 out)
// ---------------------------------------------------------------------------
__global__ __launch_bounds__(256) void gemm_mfma(const float* __restrict__ A,
                                                 const float* __restrict__ W,
                                                 float* __restrict__ C) {
    __shared__ unsigned short As[64 * 72];
    __shared__ unsigned short Ws[48 * 72];
    const int t = threadIdx.x;
    const int w = t >> 6, lane = t & 63, lr = lane & 15, lg = lane >> 4;
    const int m0 = blockIdx.x * 64;
    const int n0 = blockIdx.y * 48;

    f32x4 acc[3];
#pragma unroll
    for (int ct = 0; ct < 3; ++ct) acc[ct] = (f32x4){0.f, 0.f, 0.f, 0.f};

    for (int k0 = 0; k0 < EE; k0 += 32) {
        {
            int row = t >> 2, cb = t & 3;
            const float* src = A + (size_t)(m0 + row) * EE + k0 + cb * 8;
            f32x4 a = *(const f32x4*)src, b = *(const f32x4*)(src + 4);
            *(bf16x8*)&As[row * 72 + cb * 8] = cvt8(a, b);
        }
        if (t < 192) {
            int row = t >> 2, cb = t & 3;
            const float* src = W + (size_t)(n0 + row) * EE + k0 + cb * 8;
            f32x4 a = *(const f32x4*)src, b = *(const f32x4*)(src + 4);
            *(bf16x8*)&Ws[row * 72 + cb * 8] = cvt8(a, b);
        }
        __syncthreads();
        bf16x8 a = *(const bf16x8*)&As[(w * 16 + lr) * 72 + lg * 8];
#pragma unroll
        for (int ct = 0; ct < 3; ++ct) {
            bf16x8 b = *(const bf16x8*)&Ws[(ct * 16 + lr) * 72 + lg * 8];
            acc[ct] = __builtin_amdgcn_mfma_f32_16x16x32_bf16(a, b, acc[ct], 0, 0, 0);
        }
        __syncthreads();
    }
#pragma unroll
    for (int ct = 0; ct < 3; ++ct)
#pragma unroll
        for (int r = 0; r < 4; ++r)
            C[(size_t)(m0 + w * 16 + lg * 4 + r) * EE + n0 + ct * 16 + lr] = acc[ct][r];
}

__global__ __launch_bounds__(256) void zero_f32(float* __restrict__ p, int n4) {
    int i = blockIdx.x * 256 + threadIdx.x;
    if (i < n4) ((float4*)p)[i] = make_float4(0.f, 0.f, 0.f, 0.f);
}

// ---------------------------------------------------------------------------
// MFMA attention v13 = r20 + separate K/Vt LDS buffers (59.5 KB — occupancy
// is register-pinned at 2 blocks/CU so the 80 KB/block LDS budget is free).
// Barrier-dataflow consequences (audited):
//  - B2 (K/Vt union WAR) GONE: each wave writes Vt b1 right after its own
//    softmax; other waves' QK reads hit K_s (disjoint).
//  - B0 GONE: after B4, remaining LDS ops are PV23 reads of Vt_s, disjoint
//    from next frame's K_s/bias_s writes -> cross-frame overlap for free.
//  - All remaining barriers (B1/B3/B4) lgkm-only: no vmcnt drain anywhere.
// 3 barriers/frame (was 5). Registers byte-identical to r20 (VGPR ~120).
// All other structure r20: swapped QK 16x16x32, register softmax with inv
// folded into bf16 pack, pk = 16x16x16 PV A-fragment, mix C-accum, FPB=4,
// V b1 issued before QK, mask prefetched one frame ahead, (256,2).
// ---------------------------------------------------------------------------
__global__ __launch_bounds__(256, 2) void attn_mfma(const float* __restrict__ qs_g,
                                                    const float* __restrict__ k_g,
                                                    const float* __restrict__ v_g,
                                                    const int* __restrict__ m_g,
                                                    float* __restrict__ mix_g) {
    const int h = blockIdx.x, fg = blockIdx.y, n = blockIdx.z;

    __shared__ __attribute__((aligned(16))) unsigned short K_s[KROWS * 64];  // [208][64] swz
    __shared__ __attribute__((aligned(16))) unsigned short Vt_s[64 * VST];   // [64][256] swz
    __shared__ __attribute__((aligned(16))) float bias_s[224];

    const int t = threadIdx.x;
    const int w = t >> 6, lane = t & 63, lr = lane & 15, lg = lane >> 4;

    // Q fragments straight to registers (scaled by d^-0.5)
    bf16x8 qb0, qb1;
    {
        const float* qp = qs_g + ((size_t)n * QN + w * 16 + lr) * EE + h * DH + lg * 8;
        f32x4 a = *(const f32x4*)qp, b = *(const f32x4*)(qp + 4);
        f32x4 c = *(const f32x4*)(qp + 32), d = *(const f32x4*)(qp + 36);
#pragma unroll
        for (int i = 0; i < 4; ++i) { a[i] *= 0.125f; b[i] *= 0.125f; c[i] *= 0.125f; d[i] *= 0.125f; }
        qb0 = cvt8(a, b);
        qb1 = cvt8(c, d);
    }

    // mask for frame 0 (prefetched; subsequent frames prefetched in-loop)
    int mr = (t < LP) ? m_g[(size_t)n * KLEN + (size_t)(fg * FPB) * LP + t] : 0;

    float mix[4][4];  // PV accumulator across kt AND frames (inv pre-folded into pk)
#pragma unroll
    for (int dt = 0; dt < 4; ++dt)
#pragma unroll
        for (int r = 0; r < 4; ++r) mix[dt][r] = 0.f;

    for (int ff = 0; ff < FPB; ++ff) {
        const size_t kbase = (size_t)n * KLEN + (size_t)(fg * FPB + ff) * LP;

        // ---- stage K [208][64] bf16, XOR-swizzled (g = p&7); no B0 needed:
        //      K_s/bias_s are disjoint from Vt_s which PV23 stragglers read ----
#pragma unroll
        for (int u = 0; u < 7; ++u) {
            int unit = t + 256 * u;
            if (unit < KROWS * 8) {
                int p = unit >> 3, blk = unit & 7;
                f32x4 a = {0.f, 0.f, 0.f, 0.f}, b = {0.f, 0.f, 0.f, 0.f};
                if (p < LP) {
                    const float* src = k_g + ((kbase + p) * HN + h) * DH + blk * 8;
                    a = *(const f32x4*)src;
                    b = *(const f32x4*)(src + 4);
                }
                *(bf16x8*)&K_s[p * 64 + ((blk ^ (p & 7)) << 3)] = cvt8(a, b);
            }
        }
        if (t < 224) bias_s[t] = (t < LP && mr != 0) ? 0.f : -1e30f;  // mr prefetched
        barrier_lds_only();  // B1: K + bias visible (ds_writes committed via lgkmcnt)

        // ---- issue V batch1 loads (d in [0,32)) — overlap QK + softmax ----
        f32x4 va[4], vb[4];
#pragma unroll
        for (int u = 0; u < 4; ++u) {
            int unit = t + 256 * u;
            int pp = unit >> 3, d4 = unit & 7;
            int p0 = pp * 2;
            va[u] = (f32x4){0.f, 0.f, 0.f, 0.f};
            vb[u] = (f32x4){0.f, 0.f, 0.f, 0.f};
            if (p0 < LP) {
                const float* vg = v_g + ((kbase + p0) * HN + h) * DH + d4 * 4;
                va[u] = *(const f32x4*)vg;
                if (p0 + 1 < LP) vb[u] = *(const f32x4*)(vg + (size_t)HN * DH);
            }
        }
        // ---- prefetch next frame's mask (1 int, in flight through the frame) ----
        if (ff + 1 < FPB) mr = (t < LP) ? m_g[kbase + LP + t] : 0;

        // ---- QK^T: lane holds scores for q = w*16+lr, p = tl*16 + lg*4 + r ----
        f32x4 sc[13];
        __builtin_amdgcn_s_setprio(1);
#pragma unroll
        for (int tl = 0; tl < 13; ++tl) {
            int row = tl * 16 + lr;
            bf16x8 a0 = *(const bf16x8*)&K_s[row * 64 + ((lg ^ (lr & 7)) << 3)];
            bf16x8 a1 = *(const bf16x8*)&K_s[row * 64 + (((4 + lg) ^ (lr & 7)) << 3)];
            f32x4 z = {0.f, 0.f, 0.f, 0.f};
            z = __builtin_amdgcn_mfma_f32_16x16x32_bf16(a0, qb0, z, 0, 0, 0);
            sc[tl] = __builtin_amdgcn_mfma_f32_16x16x32_bf16(a1, qb1, z, 0, 0, 0);
        }
        __builtin_amdgcn_s_setprio(0);

        // ---- register softmax over 208 patches ----
        float mx = -FLT_MAX;
#pragma unroll
        for (int tl = 0; tl < 13; ++tl) {
            f32x4 bv = *(const f32x4*)&bias_s[tl * 16 + lg * 4];
#pragma unroll
            for (int r = 0; r < 4; ++r) {
                float sv = sc[tl][r] + bv[r];
                sc[tl][r] = sv;
                mx = fmaxf(mx, sv);
            }
        }
        mx = fmaxf(mx, __shfl_xor(mx, 16));
        mx = fmaxf(mx, __shfl_xor(mx, 32));
        float sum = 0.f;
#pragma unroll
        for (int tl = 0; tl < 13; ++tl) {
            float e0 = __expf(sc[tl][0] - mx);
            float e1 = __expf(sc[tl][1] - mx);
            float e2 = __expf(sc[tl][2] - mx);
            float e3 = __expf(sc[tl][3] - mx);
            sum += (e0 + e1) + (e2 + e3);
            sc[tl][0] = e0; sc[tl][1] = e1; sc[tl][2] = e2; sc[tl][3] = e3;
        }
        sum += __shfl_xor(sum, 16);
        sum += __shfl_xor(sum, 32);
        float inv = 1.0f / sum;
        unsigned pk[13][2];
#pragma unroll
        for (int tl = 0; tl < 13; ++tl) {
            pk[tl][0] = pkbf(sc[tl][0] * inv, sc[tl][1] * inv);
            pk[tl][1] = pkbf(sc[tl][2] * inv, sc[tl][3] * inv);
        }

        // ---- write Vt batch1 (rows 0..31) immediately — no barrier needed:
        //      other waves still in QK read K_s (disjoint buffer) ----
        // swizzle g(row)=(row+2*(row>>2))&7; write guard p0 < KROWS zeros pads
#pragma unroll
        for (int u = 0; u < 4; ++u) {
            int unit = t + 256 * u;
            int pp = unit >> 3, d4 = unit & 7;
            int p0 = pp * 2;
            if (p0 < KROWS) {
                int blk = p0 >> 3, sub = p0 & 7;
#pragma unroll
                for (int i = 0; i < 4; ++i) {
                    int row = d4 * 4 + i;
                    int g = (row + 2 * (row >> 2)) & 7;
                    *(unsigned*)&Vt_s[row * VST + (((blk ^ g) << 3) | sub)] = pkbf(va[u][i], vb[u][i]);
                }
            }
        }
        // ---- issue V batch2 loads (d in [32,64)) — stay in flight across B3 ----
#pragma unroll
        for (int u = 0; u < 4; ++u) {
            int unit = t + 256 * u;
            int pp = unit >> 3, d4 = unit & 7;
            int p0 = pp * 2;
            va[u] = (f32x4){0.f, 0.f, 0.f, 0.f};
            vb[u] = (f32x4){0.f, 0.f, 0.f, 0.f};
            if (p0 < LP) {
                const float* vg = v_g + ((kbase + p0) * HN + h) * DH + (8 + d4) * 4;
                va[u] = *(const f32x4*)vg;
                if (p0 + 1 < LP) vb[u] = *(const f32x4*)(vg + (size_t)HN * DH);
            }
        }
        barrier_lds_only();  // B3: all waves' Vt rows 0..31 visible; vmcnt NOT drained

        // ---- PV dt=0,1: A = pk fragments (16x16x16), C accumulator = mix ----
        __builtin_amdgcn_s_setprio(1);
#pragma unroll
        for (int dt = 0; dt < 2; ++dt) {
            int row = dt * 16 + lr;
            int g = (row + 2 * (row >> 2)) & 7;
            f32x4 acc = {mix[dt][0], mix[dt][1], mix[dt][2], mix[dt][3]};
#pragma unroll
            for (int kt = 0; kt < 13; ++kt) {
                int c0 = kt * 16 + lg * 4;
                s16x4 b = *(const s16x4*)&Vt_s[row * VST + ((((c0 >> 3) ^ g) << 3) | (c0 & 7))];
                s16x4 a = __builtin_bit_cast(s16x4, (u32x2){pk[kt][0], pk[kt][1]});
                acc = mfma16(a, b, acc);
            }
#pragma unroll
            for (int r = 0; r < 4; ++r) mix[dt][r] = acc[r];
        }
        __builtin_amdgcn_s_setprio(0);

        // ---- write Vt batch2 (rows 32..63) — compiler inserts vmcnt wait ----
#pragma unroll
        for (int u = 0; u < 4; ++u) {
            int unit = t + 256 * u;
            int pp = unit >> 3, d4 = unit & 7;
            int p0 = pp * 2;
            if (p0 < KROWS) {
                int blk = p0 >> 3, sub = p0 & 7;
#pragma unroll
                for (int i = 0; i < 4; ++i) {
                    int row = 32 + d4 * 4 + i;
                    int g = (row + 2 * (row >> 2)) & 7;
                    *(unsigned*)&Vt_s[row * VST + (((blk ^ g) << 3) | sub)] = pkbf(va[u][i], vb[u][i]);
                }
            }
        }
        barrier_lds_only();  // B4: Vt rows 32..63 visible

        // ---- PV dt=2,3 (stragglers overlap next frame's K staging) ----
        __builtin_amdgcn_s_setprio(1);
#pragma unroll
        for (int dt = 2; dt < 4; ++dt) {
            int row = dt * 16 + lr;
            int g = (row + 2 * (row >> 2)) & 7;
            f32x4 acc = {mix[dt][0], mix[dt][1], mix[dt][2], mix[dt][3]};
#pragma unroll
            for (int kt = 0; kt < 13; ++kt) {
                int c0 = kt * 16 + lg * 4;
                s16x4 b = *(const s16x4*)&Vt_s[row * VST + ((((c0 >> 3) ^ g) << 3) | (c0 & 7))];
                s16x4 a = __builtin_bit_cast(s16x4, (u32x2){pk[kt][0], pk[kt][1]});
                acc = mfma16(a, b, acc);
            }
#pragma unroll
            for (int r = 0; r < 4; ++r) mix[dt][r] = acc[r];
        }
        __builtin_amdgcn_s_setprio(0);
    }

    // ---- accumulate into mix[n][q = w*16 + lg*4 + r][h*64 + dt*16 + lr] ----
#pragma unroll
    for (int dt = 0; dt < 4; ++dt)
#pragma unroll
        for (int r = 0; r < 4; ++r)
            atomicAdd(mix_g + ((size_t)n * QN + w * 16 + lg * 4 + r) * EE + h * DH + dt * 16 + lr,
                      mix[dt][r]);
}

// ---------------------------------------------------------------------------
extern "C" void kernel_launch(void* const* d_in, const int* in_sizes, int n_in,
                              void* d_out, int out_size, void* d_ws, size_t ws_size,
                              hipStream_t stream) {
    const float* q  = (const float*)d_in[0];
    const float* k  = (const float*)d_in[1];
    const float* v  = (const float*)d_in[2];
    const int*   m  = (const int*)d_in[3];
    const float* Wi = (const float*)d_in[4];
    const float* Wo = (const float*)d_in[5];

    float* out = (float*)d_out;
    float* qs  = out + (size_t)N_B * QN * EE;  // second output (qs_out), also attn input
    float* mix = (float*)d_ws;                 // 2048x768 fp32 scratch (atomic-accumulated)

    const int mix_n4 = (N_B * QN * EE) / 4;
    dim3 ggrid((N_B * QN) / 64, EE / 48);
    gemm_mfma<<<ggrid, 256, 0, stream>>>(q, Wi, qs);                                 // in-proj
    zero_f32<<<(mix_n4 + 255) / 256, 256, 0, stream>>>(mix, mix_n4);                 // zero mix
    attn_mfma<<<dim3(HN, FN / FPB, N_B), 256, 0, stream>>>(qs, k, v, m, mix);        // attention
    gemm_mfma<<<ggrid, 256, 0, stream>>>(mix, Wo, out);                              // out-proj
}

// Round 22
// 201.640 us; speedup vs baseline: 1.0097x; 1.0097x over previous
//
#include <hip/hip_runtime.h>
#include <hip/hip_bf16.h>
#include <cfloat>

// dims
#define N_B 32
#define QN 64
#define FN 16
#define LP 196
#define HN 12
#define DH 64
#define EE 768
#define KLEN 3136
#define FPB 4          // frames per block (attn): 12*4*32 = 1536 blocks = 3.0 CU-rounds @2/CU
#define KROWS 208      // padded patches per frame for QK (13*16)
#define VST 256        // Vt_s row stride in bf16 (512B, pow2 for XOR swizzle)

typedef short s16x4 __attribute__((ext_vector_type(4)));
typedef __bf16 bf16x4 __attribute__((ext_vector_type(4)));
typedef __bf16 bf16x8 __attribute__((ext_vector_type(8)));
typedef float f32x4 __attribute__((ext_vector_type(4)));
typedef unsigned u32x2 __attribute__((ext_vector_type(2)));

__device__ __forceinline__ bf16x8 cvt8(f32x4 a, f32x4 b) {
    bf16x8 r;
    r[0] = (__bf16)a[0]; r[1] = (__bf16)a[1]; r[2] = (__bf16)a[2]; r[3] = (__bf16)a[3];
    r[4] = (__bf16)b[0]; r[5] = (__bf16)b[1]; r[6] = (__bf16)b[2]; r[7] = (__bf16)b[3];
    return r;
}
__device__ __forceinline__ unsigned short bfb(float x) {
    return __builtin_bit_cast(unsigned short, (__bf16)x);
}
__device__ __forceinline__ unsigned pkbf(float lo, float hi) {
    return (unsigned)bfb(lo) | ((unsigned)bfb(hi) << 16);
}
// raw workgroup barrier that does NOT drain vmcnt (LDS ordering only).
__device__ __forceinline__ void barrier_lds_only() {
    asm volatile("s_waitcnt lgkmcnt(0)" ::: "memory");
    __builtin_amdgcn_s_barrier();
    __builtin_amdgcn_sched_barrier(0);  // rule #18: nothing hoists past the waitcnt
}

// 16x16x16 bf16 MFMA with name-portability fallback
__device__ __forceinline__ f32x4 mfma16(s16x4 a, s16x4 b, f32x4 c) {
#if __has_builtin(__builtin_amdgcn_mfma_f32_16x16x16_bf16)
    return __builtin_amdgcn_mfma_f32_16x16x16_bf16(__builtin_bit_cast(bf16x4, a),
                                                   __builtin_bit_cast(bf16x4, b), c, 0, 0, 0);
#elif __has_builtin(__builtin_amdgcn_mfma_f32_16x16x16bf16_1k)
    return __builtin_amdgcn_mfma_f32_16x16x16bf16_1k(a, b, c, 0, 0, 0);
#else
    f32x4 d;
    asm volatile("v_mfma_f32_16x16x16_bf16 %0, %1, %2, %3"
                 : "=v"(d) : "v"(a), "v"(b), "v"(c));
    return d;
#endif
}

// ---------------------------------------------------------------------------
// bf16 MFMA GEMM: C[m][n] = sum_k A[m][k] * W[n][k]  (fp32 in, fp32 out)
// ---------------------------------------------------------------------------
__global__ __launch_bounds__(256) void gemm_mfma(const float* __restrict__ A,
                                                 const float* __restrict__ W,
                                                 float* __restrict__ C) {
    __shared__ unsigned short As[64 * 72];
    __shared__ unsigned short Ws[48 * 72];
    const int t = threadIdx.x;
    const int w = t >> 6, lane = t & 63, lr = lane & 15, lg = lane >> 4;
    const int m0 = blockIdx.x * 64;
    const int n0 = blockIdx.y * 48;

    f32x4 acc[3];
#pragma unroll
    for (int ct = 0; ct < 3; ++ct) acc[ct] = (f32x4){0.f, 0.f, 0.f, 0.f};

    for (int k0 = 0; k0 < EE; k0 += 32) {
        {
            int row = t >> 2, cb = t & 3;
            const float* src = A + (size_t)(m0 + row) * EE + k0 + cb * 8;
            f32x4 a = *(const f32x4*)src, b = *(const f32x4*)(src + 4);
            *(bf16x8*)&As[row * 72 + cb * 8] = cvt8(a, b);
        }
        if (t < 192) {
            int row = t >> 2, cb = t & 3;
            const float* src = W + (size_t)(n0 + row) * EE + k0 + cb * 8;
            f32x4 a = *(const f32x4*)src, b = *(const f32x4*)(src + 4);
            *(bf16x8*)&Ws[row * 72 + cb * 8] = cvt8(a, b);
        }
        __syncthreads();
        bf16x8 a = *(const bf16x8*)&As[(w * 16 + lr) * 72 + lg * 8];
#pragma unroll
        for (int ct = 0; ct < 3; ++ct) {
            bf16x8 b = *(const bf16x8*)&Ws[(ct * 16 + lr) * 72 + lg * 8];
            acc[ct] = __builtin_amdgcn_mfma_f32_16x16x32_bf16(a, b, acc[ct], 0, 0, 0);
        }
        __syncthreads();
    }
#pragma unroll
    for (int ct = 0; ct < 3; ++ct)
#pragma unroll
        for (int r = 0; r < 4; ++r)
            C[(size_t)(m0 + w * 16 + lg * 4 + r) * EE + n0 + ct * 16 + lr] = acc[ct][r];
}

__global__ __launch_bounds__(256) void zero_f32(float* __restrict__ p, int n4) {
    int i = blockIdx.x * 256 + threadIdx.x;
    if (i < n4) ((float4*)p)[i] = make_float4(0.f, 0.f, 0.f, 0.f);
}

// ---------------------------------------------------------------------------
// MFMA attention (FINAL = r20, measured best 199.5us total, no spill).
// Union KV LDS 33.8 KB; swapped QK 16x16x32 -> scores in regs; register
// softmax with inv folded into bf16 pack; pk doubles as the 16x16x16 PV
// A-fragment (QK C-layout == PV A-layout: zero data movement); mix[] is
// the PV C accumulator; FPB=4 amortizes Q loads + atomics; V batch1 issued
// before QK (overlaps compute); mask prefetched one frame ahead; B3/B4 raw
// lgkm-only barriers (V batch2 loads stay in flight under PV dt01).
// Design-space map (21 rounds): occupancy >2 blocks/CU -> spill (r7/r12/r13);
// register-funded K prefetch -> spill (r5/r15/r17); direct-global K ->
// regression (r18); barrier restructuring -> neutral (r11/r16/r21).
// ---------------------------------------------------------------------------
__global__ __launch_bounds__(256, 2) void attn_mfma(const float* __restrict__ qs_g,
                                                    const float* __restrict__ k_g,
                                                    const float* __restrict__ v_g,
                                                    const int* __restrict__ m_g,
                                                    float* __restrict__ mix_g) {
    const int h = blockIdx.x, fg = blockIdx.y, n = blockIdx.z;

    __shared__ __attribute__((aligned(16))) unsigned short KV_s[64 * VST]; // K view: [208][64] swz; Vt view: [64][256] swz
    __shared__ __attribute__((aligned(16))) float bias_s[224];

    const int t = threadIdx.x;
    const int w = t >> 6, lane = t & 63, lr = lane & 15, lg = lane >> 4;

    // Q fragments straight to registers (scaled by d^-0.5)
    bf16x8 qb0, qb1;
    {
        const float* qp = qs_g + ((size_t)n * QN + w * 16 + lr) * EE + h * DH + lg * 8;
        f32x4 a = *(const f32x4*)qp, b = *(const f32x4*)(qp + 4);
        f32x4 c = *(const f32x4*)(qp + 32), d = *(const f32x4*)(qp + 36);
#pragma unroll
        for (int i = 0; i < 4; ++i) { a[i] *= 0.125f; b[i] *= 0.125f; c[i] *= 0.125f; d[i] *= 0.125f; }
        qb0 = cvt8(a, b);
        qb1 = cvt8(c, d);
    }

    // mask for frame 0 (prefetched; subsequent frames prefetched in-loop)
    int mr = (t < LP) ? m_g[(size_t)n * KLEN + (size_t)(fg * FPB) * LP + t] : 0;

    float mix[4][4];  // PV accumulator across kt AND frames (inv pre-folded into pk)
#pragma unroll
    for (int dt = 0; dt < 4; ++dt)
#pragma unroll
        for (int r = 0; r < 4; ++r) mix[dt][r] = 0.f;

    for (int ff = 0; ff < FPB; ++ff) {
        const size_t kbase = (size_t)n * KLEN + (size_t)(fg * FPB + ff) * LP;

        __syncthreads();  // B0: prev-frame PV readers done before K overwrite

        // ---- stage K [208][64] bf16, XOR-swizzled 16B blocks (g = p&7) ----
#pragma unroll
        for (int u = 0; u < 7; ++u) {
            int unit = t + 256 * u;
            if (unit < KROWS * 8) {
                int p = unit >> 3, blk = unit & 7;
                f32x4 a = {0.f, 0.f, 0.f, 0.f}, b = {0.f, 0.f, 0.f, 0.f};
                if (p < LP) {
                    const float* src = k_g + ((kbase + p) * HN + h) * DH + blk * 8;
                    a = *(const f32x4*)src;
                    b = *(const f32x4*)(src + 4);
                }
                *(bf16x8*)&KV_s[p * 64 + ((blk ^ (p & 7)) << 3)] = cvt8(a, b);
            }
        }
        if (t < 224) bias_s[t] = (t < LP && mr != 0) ? 0.f : -1e30f;  // mr prefetched
        __syncthreads();  // B1: K + bias visible

        // ---- issue V batch1 loads (d in [0,32)) — overlap QK + softmax ----
        f32x4 va[4], vb[4];
#pragma unroll
        for (int u = 0; u < 4; ++u) {
            int unit = t + 256 * u;
            int pp = unit >> 3, d4 = unit & 7;
            int p0 = pp * 2;
            va[u] = (f32x4){0.f, 0.f, 0.f, 0.f};
            vb[u] = (f32x4){0.f, 0.f, 0.f, 0.f};
            if (p0 < LP) {
                const float* vg = v_g + ((kbase + p0) * HN + h) * DH + d4 * 4;
                va[u] = *(const f32x4*)vg;
                if (p0 + 1 < LP) vb[u] = *(const f32x4*)(vg + (size_t)HN * DH);
            }
        }
        // ---- prefetch next frame's mask (1 int, in flight through the frame) ----
        if (ff + 1 < FPB) mr = (t < LP) ? m_g[kbase + LP + t] : 0;

        // ---- QK^T: lane holds scores for q = w*16+lr, p = tl*16 + lg*4 + r ----
        f32x4 sc[13];
        __builtin_amdgcn_s_setprio(1);
#pragma unroll
        for (int tl = 0; tl < 13; ++tl) {
            int row = tl * 16 + lr;
            bf16x8 a0 = *(const bf16x8*)&KV_s[row * 64 + ((lg ^ (lr & 7)) << 3)];
            bf16x8 a1 = *(const bf16x8*)&KV_s[row * 64 + (((4 + lg) ^ (lr & 7)) << 3)];
            f32x4 z = {0.f, 0.f, 0.f, 0.f};
            z = __builtin_amdgcn_mfma_f32_16x16x32_bf16(a0, qb0, z, 0, 0, 0);
            sc[tl] = __builtin_amdgcn_mfma_f32_16x16x32_bf16(a1, qb1, z, 0, 0, 0);
        }
        __builtin_amdgcn_s_setprio(0);

        // ---- register softmax over 208 patches ----
        float mx = -FLT_MAX;
#pragma unroll
        for (int tl = 0; tl < 13; ++tl) {
            f32x4 bv = *(const f32x4*)&bias_s[tl * 16 + lg * 4];
#pragma unroll
            for (int r = 0; r < 4; ++r) {
                float sv = sc[tl][r] + bv[r];
                sc[tl][r] = sv;
                mx = fmaxf(mx, sv);
            }
        }
        mx = fmaxf(mx, __shfl_xor(mx, 16));
        mx = fmaxf(mx, __shfl_xor(mx, 32));
        float sum = 0.f;
#pragma unroll
        for (int tl = 0; tl < 13; ++tl) {
            float e0 = __expf(sc[tl][0] - mx);
            float e1 = __expf(sc[tl][1] - mx);
            float e2 = __expf(sc[tl][2] - mx);
            float e3 = __expf(sc[tl][3] - mx);
            sum += (e0 + e1) + (e2 + e3);
            sc[tl][0] = e0; sc[tl][1] = e1; sc[tl][2] = e2; sc[tl][3] = e3;
        }
        sum += __shfl_xor(sum, 16);
        sum += __shfl_xor(sum, 32);
        float inv = 1.0f / sum;
        unsigned pk[13][2];
#pragma unroll
        for (int tl = 0; tl < 13; ++tl) {
            pk[tl][0] = pkbf(sc[tl][0] * inv, sc[tl][1] * inv);
            pk[tl][1] = pkbf(sc[tl][2] * inv, sc[tl][3] * inv);
        }

        __syncthreads();  // B2: all waves' QK reads of K done

        // ---- write Vt batch1 (rows 0..31), swizzled g(row)=(row+2*(row>>2))&7 ----
        // write guard p0 < KROWS: pad pairs [196,208) get explicit zeros
#pragma unroll
        for (int u = 0; u < 4; ++u) {
            int unit = t + 256 * u;
            int pp = unit >> 3, d4 = unit & 7;
            int p0 = pp * 2;
            if (p0 < KROWS) {
                int blk = p0 >> 3, sub = p0 & 7;
#pragma unroll
                for (int i = 0; i < 4; ++i) {
                    int row = d4 * 4 + i;
                    int g = (row + 2 * (row >> 2)) & 7;
                    *(unsigned*)&KV_s[row * VST + (((blk ^ g) << 3) | sub)] = pkbf(va[u][i], vb[u][i]);
                }
            }
        }
        // ---- issue V batch2 loads (d in [32,64)) — stay in flight across B3 ----
#pragma unroll
        for (int u = 0; u < 4; ++u) {
            int unit = t + 256 * u;
            int pp = unit >> 3, d4 = unit & 7;
            int p0 = pp * 2;
            va[u] = (f32x4){0.f, 0.f, 0.f, 0.f};
            vb[u] = (f32x4){0.f, 0.f, 0.f, 0.f};
            if (p0 < LP) {
                const float* vg = v_g + ((kbase + p0) * HN + h) * DH + (8 + d4) * 4;
                va[u] = *(const f32x4*)vg;
                if (p0 + 1 < LP) vb[u] = *(const f32x4*)(vg + (size_t)HN * DH);
            }
        }
        barrier_lds_only();  // B3: Vt rows 0..31 visible; vmcnt NOT drained

        // ---- PV dt=0,1: A = pk fragments (16x16x16), C accumulator = mix ----
        __builtin_amdgcn_s_setprio(1);
#pragma unroll
        for (int dt = 0; dt < 2; ++dt) {
            int row = dt * 16 + lr;
            int g = (row + 2 * (row >> 2)) & 7;
            f32x4 acc = {mix[dt][0], mix[dt][1], mix[dt][2], mix[dt][3]};
#pragma unroll
            for (int kt = 0; kt < 13; ++kt) {
                int c0 = kt * 16 + lg * 4;
                s16x4 b = *(const s16x4*)&KV_s[row * VST + ((((c0 >> 3) ^ g) << 3) | (c0 & 7))];
                s16x4 a = __builtin_bit_cast(s16x4, (u32x2){pk[kt][0], pk[kt][1]});
                acc = mfma16(a, b, acc);
            }
#pragma unroll
            for (int r = 0; r < 4; ++r) mix[dt][r] = acc[r];
        }
        __builtin_amdgcn_s_setprio(0);

        // ---- write Vt batch2 (rows 32..63; K rows 128..207 dead since B2) ----
        // compiler inserts the precise vmcnt wait on va/vb here
#pragma unroll
        for (int u = 0; u < 4; ++u) {
            int unit = t + 256 * u;
            int pp = unit >> 3, d4 = unit & 7;
            int p0 = pp * 2;
            if (p0 < KROWS) {
                int blk = p0 >> 3, sub = p0 & 7;
#pragma unroll
                for (int i = 0; i < 4; ++i) {
                    int row = 32 + d4 * 4 + i;
                    int g = (row + 2 * (row >> 2)) & 7;
                    *(unsigned*)&KV_s[row * VST + (((blk ^ g) << 3) | sub)] = pkbf(va[u][i], vb[u][i]);
                }
            }
        }
        barrier_lds_only();  // B4: Vt rows 32..63 visible (no loads outstanding)

        // ---- PV dt=2,3 ----
        __builtin_amdgcn_s_setprio(1);
#pragma unroll
        for (int dt = 2; dt < 4; ++dt) {
            int row = dt * 16 + lr;
            int g = (row + 2 * (row >> 2)) & 7;
            f32x4 acc = {mix[dt][0], mix[dt][1], mix[dt][2], mix[dt][3]};
#pragma unroll
            for (int kt = 0; kt < 13; ++kt) {
                int c0 = kt * 16 + lg * 4;
                s16x4 b = *(const s16x4*)&KV_s[row * VST + ((((c0 >> 3) ^ g) << 3) | (c0 & 7))];
                s16x4 a = __builtin_bit_cast(s16x4, (u32x2){pk[kt][0], pk[kt][1]});
                acc = mfma16(a, b, acc);
            }
#pragma unroll
            for (int r = 0; r < 4; ++r) mix[dt][r] = acc[r];
        }
        __builtin_amdgcn_s_setprio(0);
    }

    // ---- accumulate into mix[n][q = w*16 + lg*4 + r][h*64 + dt*16 + lr] ----
#pragma unroll
    for (int dt = 0; dt < 4; ++dt)
#pragma unroll
        for (int r = 0; r < 4; ++r)
            atomicAdd(mix_g + ((size_t)n * QN + w * 16 + lg * 4 + r) * EE + h * DH + dt * 16 + lr,
                      mix[dt][r]);
}

// ---------------------------------------------------------------------------
extern "C" void kernel_launch(void* const* d_in, const int* in_sizes, int n_in,
                              void* d_out, int out_size, void* d_ws, size_t ws_size,
                              hipStream_t stream) {
    const float* q  = (const float*)d_in[0];
    const float* k  = (const float*)d_in[1];
    const float* v  = (const float*)d_in[2];
    const int*   m  = (const int*)d_in[3];
    const float* Wi = (const float*)d_in[4];
    const float* Wo = (const float*)d_in[5];

    float* out = (float*)d_out;
    float* qs  = out + (size_t)N_B * QN * EE;  // second output (qs_out), also attn input
    float* mix = (float*)d_ws;                 // 2048x768 fp32 scratch (atomic-accumulated)

    const int mix_n4 = (N_B * QN * EE) / 4;
    dim3 ggrid((N_B * QN) / 64, EE / 48);
    gemm_mfma<<<ggrid, 256, 0, stream>>>(q, Wi, qs);                                 // in-proj
    zero_f32<<<(mix_n4 + 255) / 256, 256, 0, stream>>>(mix, mix_n4);                 // zero mix
    attn_mfma<<<dim3(HN, FN / FPB, N_B), 256, 0, stream>>>(qs, k, v, m, mix);        // attention
    gemm_mfma<<<ggrid, 256, 0, stream>>>(mix, Wo, out);                              // out-proj
}